// Round 19
// baseline (1166.218 us; speedup 1.0000x reference)
//
#include <hip/hip_runtime.h>
#include <math.h>

// Problem dims
#define B_   256
#define T_   512
#define F_   64
#define H1_  100
#define H2_  128
#define OUT_ 19
#define TCH  64             // timesteps per chunk (pipeline stage)
#define NCH  (T_/TCH)       // 8 chunks
#define NPC  512            // padded+permuted gate columns (both layers)
#define KP   128            // padded K (units) for both layers

typedef unsigned int uint;
typedef _Float16 h16;
typedef __attribute__((ext_vector_type(2))) _Float16 h16x2;
typedef __attribute__((ext_vector_type(8))) _Float16 f16x8;
typedef __attribute__((ext_vector_type(4))) float f32x4;

// ---- workspace layout (bytes) ----
#define XPW_BYTES (16ull*TCH*NPC*16*2)     // 16,777,216 per xp buffer
#define H1G_BYTES (16ull*TCH*KP*16*2)      // 4,194,304
#define CST_BYTES (16ull*KP*16*4)          // 131,072
#define HST_BYTES (16ull*KP*16*2)          // 65,536
#define UF_BYTES  (128ull*64*8*2)          // 131,072 per packed weight buffer

#define A_XP1A  0ull
#define A_XP1B  (A_XP1A + XPW_BYTES)
#define A_XP2A  (A_XP1B + XPW_BYTES)
#define A_XP2B  (A_XP2A + XPW_BYTES)
#define A_H1G   (A_XP2B + XPW_BYTES)
#define A_C1    (A_H1G  + H1G_BYTES)
#define A_C2    (A_C1   + CST_BYTES)
#define A_H1S   (A_C2   + CST_BYTES)
#define A_H2S   (A_H1S  + HST_BYTES)
#define A_U1F   (A_H2S  + HST_BYTES)
#define A_U2F   (A_U1F  + UF_BYTES)
#define A_W1F   (A_U2F  + UF_BYTES)
#define A_W2F   (A_W1F  + UF_BYTES)
#define WS_A    (A_W2F  + UF_BYTES)        // ~72.4 MB

__device__ __forceinline__ float sigm(float x) { return 1.0f / (1.0f + __expf(-x)); }

__device__ __forceinline__ uint pk2(float a, float b) {
    h16x2 h; h.x = (h16)a; h.y = (h16)b;
    return __builtin_bit_cast(uint, h);
}

__device__ __forceinline__ f32x4 mfma16(f16x8 a, f16x8 b, f32x4 c) {
    return __builtin_amdgcn_mfma_f32_16x16x32_f16(a, b, c, 0, 0, 0);
}

__device__ __forceinline__ f32x4 up4(uint2 v) {
    h16x2 a = __builtin_bit_cast(h16x2, v.x);
    h16x2 b = __builtin_bit_cast(h16x2, v.y);
    f32x4 r; r[0] = (float)a.x; r[1] = (float)a.y; r[2] = (float)b.x; r[3] = (float)b.y;
    return r;
}

// lgkm-only barrier (T4): orders LDS h-exchange without draining vmcnt.
__device__ __forceinline__ void bar_lgkm() {
    asm volatile("s_waitcnt lgkmcnt(0)" ::: "memory");
    __builtin_amdgcn_sched_barrier(0);
    __builtin_amdgcn_s_barrier();
    __builtin_amdgcn_sched_barrier(0);
}

// Strided B-fragment gather with gate-column permutation (prepack + fallback only).
__device__ __forceinline__ f16x8 load_bfrag(const float* __restrict__ P, int H, int OG,
                                            int Kreal, int ubase, int g, int q, int lane) {
    const int u  = ubase + (lane & 15);
    const int k0 = q * 32 + (lane >> 4) * 8;
    const int col = g * H + u;
    float f[8];
    #pragma unroll
    for (int e = 0; e < 8; ++e) {
        const int k = k0 + e;
        f[e] = (u < H && k < Kreal) ? P[(size_t)k * OG + col] : 0.0f;
    }
    uint4 r;
    r.x = pk2(f[0], f[1]); r.y = pk2(f[2], f[3]);
    r.z = pk2(f[4], f[5]); r.w = pk2(f[6], f[7]);
    return __builtin_bit_cast(f16x8, r);
}

// ================= weight prepack (runs once): U1,U2,W1,W2 =================
// Fragment (w,g,q) of lane l at D[(((w*4+g)*4+q)*64 + l)*8 .. +8)
__global__ __launch_bounds__(512) void k_prepack4(
    const float* __restrict__ U1, const float* __restrict__ U2,
    const float* __restrict__ W1, const float* __restrict__ W2,
    h16* __restrict__ u1f, h16* __restrict__ u2f,
    h16* __restrict__ w1f, h16* __restrict__ w2f)
{
    const int w = blockIdx.x & 7;
    const int which = blockIdx.x >> 3;   // 0:U1 1:U2 2:W1 3:W2
    const float* P; int H, K, KF; h16* D;
    if (which == 0)      { P = U1; H = H1_; K = H1_; KF = 4; D = u1f; }
    else if (which == 1) { P = U2; H = H2_; K = H2_; KF = 4; D = u2f; }
    else if (which == 2) { P = W1; H = H1_; K = 64;  KF = 2; D = w1f; }
    else                 { P = W2; H = H2_; K = H1_; KF = 4; D = w2f; }
    const int lane = threadIdx.x & 63;
    #pragma unroll
    for (int it = 0; it < 2; ++it) {
        const int combo = it * 8 + (threadIdx.x >> 6);
        const int g = combo >> 2, q = combo & 3;
        if (q < KF) {
            f16x8 fr = load_bfrag(P, H, 4 * H, K, w * 16, g, q, lane);
            *(f16x8*)(D + (size_t)(((w * 4 + g) * 4 + q) * 64 + lane) * 8) = fr;
        }
    }
}

// ================= dense pre-projection body (prepacked weights) =================
template<int MODE>
__device__ __forceinline__ void dense_body(
    const float* __restrict__ Af, const h16* __restrict__ Ah,
    const h16* __restrict__ Wf, const float* __restrict__ bias,
    const int H, const int ch, h16* __restrict__ xp,
    const int bid, const int j, const int nit)
{
    const int lane = j & 63, w = j >> 6;
    const int KF = MODE ? 4 : 2;

    f16x8 bf[4][4];
    #pragma unroll
    for (int g = 0; g < 4; ++g)
        #pragma unroll
        for (int q = 0; q < 4; ++q)
            if (q < KF)
                bf[g][q] = *(const f16x8*)(Wf + (size_t)(((w * 4 + g) * 4 + q) * 64 + lane) * 8);

    float bv[4];
    #pragma unroll
    for (int g = 0; g < 4; ++g) {
        const int u = w * 16 + (lane & 15);
        bv[g] = (u < H) ? bias[g * H + u] : 0.0f;
    }

    const int ci = lane & 15, hi = lane >> 4;
    #pragma unroll 2
    for (int it = 0; it < nit; ++it) {
        const int m = bid * nit + it;
        const int bt = m / TCH, tc = m % TCH;

        f16x8 af[4];
        if (MODE == 0) {
            const int b = bt * 16 + ci;
            const int t = ch * TCH + tc;
            #pragma unroll
            for (int q = 0; q < 2; ++q) {
                const int k0 = q * 32 + hi * 8;
                const float* p = Af + ((size_t)b * T_ + t) * F_ + k0;
                float4 x0 = *(const float4*)p;
                float4 x1 = *(const float4*)(p + 4);
                uint4 r;
                r.x = pk2(x0.x, x0.y); r.y = pk2(x0.z, x0.w);
                r.z = pk2(x1.x, x1.y); r.w = pk2(x1.z, x1.w);
                af[q] = __builtin_bit_cast(f16x8, r);
            }
        } else {
            #pragma unroll
            for (int q = 0; q < 4; ++q) {
                const int k0 = q * 32 + hi * 8;
                const size_t base = ((size_t)(bt * TCH + tc) * KP + k0) * 16 + ci;
                f16x8 a;
                #pragma unroll
                for (int e = 0; e < 8; ++e) a[e] = Ah[base + (size_t)e * 16];
                af[q] = a;
            }
        }

        f32x4 acc[4];
        #pragma unroll
        for (int g = 0; g < 4; ++g) { acc[g][0]=bv[g]; acc[g][1]=bv[g]; acc[g][2]=bv[g]; acc[g][3]=bv[g]; }
        #pragma unroll
        for (int g = 0; g < 4; ++g)
            #pragma unroll
            for (int q = 0; q < 4; ++q)
                if (q < KF) acc[g] = mfma16(af[q], bf[g][q], acc[g]);

        #pragma unroll
        for (int g = 0; g < 4; ++g) {
            const int c = (w * 4 + g) * 16 + ci;
            const size_t o = ((size_t)(bt * TCH + tc) * NPC + c) * 16 + hi * 4;
            uint2 s;
            s.x = pk2(acc[g][0], acc[g][1]);
            s.y = pk2(acc[g][2], acc[g][3]);
            *(uint2*)(xp + o) = s;
        }
    }
}

template<int MODE>
__global__ __launch_bounds__(512) void k_dense(
    const float* __restrict__ Af, const h16* __restrict__ Ah,
    const h16* __restrict__ Wf, const float* __restrict__ bias,
    const int H, const int ch, h16* __restrict__ xp)
{
    dense_body<MODE>(Af, Ah, Wf, bias, H, ch, xp, blockIdx.x, threadIdx.x, 4);
}

// ================= recurrence body (R17, unchanged) =================
#define LF(G,Q) f16x8 wf##G##Q = *(const f16x8*)(Uf + (size_t)(((w*4+G)*4+Q)*64 + lane)*8);

#define RSTEP(Pn, tcur)                                                          \
    {                                                                            \
        const int t_ = (tcur);                                                   \
        const h16* hb = &hbuf[t_ & 1][0][0];                                     \
        f16x8 a0 = *(const f16x8*)(hb + ci * 136 + 0  + hi * 8);                 \
        f16x8 a1 = *(const f16x8*)(hb + ci * 136 + 32 + hi * 8);                 \
        f16x8 a2 = *(const f16x8*)(hb + ci * 136 + 64 + hi * 8);                 \
        f16x8 a3 = *(const f16x8*)(hb + ci * 136 + 96 + hi * 8);                 \
        f32x4 z0 = up4(Pn##0), z1 = up4(Pn##1), z2 = up4(Pn##2), z3 = up4(Pn##3);\
        const uint to_ = (uint)((t_ + 2 < TCH) ? t_ + 2 : t_) * xstep;           \
        Pn##0 = *(const uint2*)(xp + xb0 + to_);                                 \
        Pn##1 = *(const uint2*)(xp + xb1 + to_);                                 \
        Pn##2 = *(const uint2*)(xp + xb2 + to_);                                 \
        Pn##3 = *(const uint2*)(xp + xb3 + to_);                                 \
        z0 = mfma16(a0, wf00, z0); z0 = mfma16(a1, wf01, z0);                    \
        z0 = mfma16(a2, wf02, z0); z0 = mfma16(a3, wf03, z0);                    \
        z1 = mfma16(a0, wf10, z1); z1 = mfma16(a1, wf11, z1);                    \
        z1 = mfma16(a2, wf12, z1); z1 = mfma16(a3, wf13, z1);                    \
        z2 = mfma16(a0, wf20, z2); z2 = mfma16(a1, wf21, z2);                    \
        z2 = mfma16(a2, wf22, z2); z2 = mfma16(a3, wf23, z2);                    \
        z3 = mfma16(a0, wf30, z3); z3 = mfma16(a1, wf31, z3);                    \
        z3 = mfma16(a2, wf32, z3); z3 = mfma16(a3, wf33, z3);                    \
        f32x4 hv;                                                                \
        _Pragma("unroll")                                                        \
        for (int i = 0; i < 4; ++i) {                                            \
            float ig = sigm(z0[i]);                                              \
            float fg = sigm(z1[i]);                                              \
            float gg = fmaxf(z2[i], 0.0f);                                       \
            float og = sigm(z3[i]);                                              \
            c[i] = fg * c[i] + ig * gg;                                          \
            hv[i] = og * fmaxf(c[i], 0.0f);                                      \
        }                                                                        \
        h16 h0 = (h16)hv[0], h1 = (h16)hv[1], h2 = (h16)hv[2], h3 = (h16)hv[3]; \
        const int nb_ = (t_ & 1) ^ 1;                                            \
        hbuf[nb_][r0 + 0][myu] = h0;                                             \
        hbuf[nb_][r0 + 1][myu] = h1;                                             \
        hbuf[nb_][r0 + 2][myu] = h2;                                             \
        hbuf[nb_][r0 + 3][myu] = h3;                                             \
        h16x2 p01_; p01_.x = h0; p01_.y = h1;                                    \
        h16x2 p23_; p23_.x = h2; p23_.y = h3;                                    \
        hp.x = __builtin_bit_cast(uint, p01_);                                   \
        hp.y = __builtin_bit_cast(uint, p23_);                                   \
        if (do_hout) *(uint2*)(hout + hob + (uint)t_ * hstep) = hp;              \
        bar_lgkm();                                                              \
    }

__device__ __forceinline__ void rec_body(
    const h16* __restrict__ Uf,
    const h16* __restrict__ xp, h16* __restrict__ hout, const int do_hout,
    float* __restrict__ cstate, h16* __restrict__ hstate, const int ch,
    const int bt, const int j)
{
    __shared__ h16 hbuf[2][16][136];
    const int lane = j & 63, w = j >> 6;
    const int ci = lane & 15, hi = lane >> 4;
    const int myu = w * 16 + ci;
    const int r0 = hi * 4;

    LF(0,0) LF(0,1) LF(0,2) LF(0,3)
    LF(1,0) LF(1,1) LF(1,2) LF(1,3)
    LF(2,0) LF(2,1) LF(2,2) LF(2,3)
    LF(3,0) LF(3,1) LF(3,2) LF(3,3)

    {
        const int u = j & 127, rr = (j >> 7) * 4;
        #pragma unroll
        for (int i = 0; i < 4; ++i) {
            h16 v = (h16)0.0f;
            if (ch != 0) v = hstate[((size_t)bt * KP + u) * 16 + rr + i];
            hbuf[0][rr + i][u] = v;
        }
    }
    f32x4 c;
    const size_t coff = ((size_t)bt * KP + myu) * 16 + r0;
    if (ch == 0) { c[0]=0.f; c[1]=0.f; c[2]=0.f; c[3]=0.f; }
    else         { c = *(const f32x4*)(cstate + coff); }
    __syncthreads();

    const uint xstep = NPC * 16;
    const uint xb0 = (uint)(((size_t)bt * TCH) * NPC + (w * 64 + ci)) * 16 + r0;
    const uint xb1 = xb0 + 16 * 16, xb2 = xb0 + 32 * 16, xb3 = xb0 + 48 * 16;

    uint2 pA0 = *(const uint2*)(xp + xb0);
    uint2 pA1 = *(const uint2*)(xp + xb1);
    uint2 pA2 = *(const uint2*)(xp + xb2);
    uint2 pA3 = *(const uint2*)(xp + xb3);
    uint2 pB0 = *(const uint2*)(xp + xb0 + xstep);
    uint2 pB1 = *(const uint2*)(xp + xb1 + xstep);
    uint2 pB2 = *(const uint2*)(xp + xb2 + xstep);
    uint2 pB3 = *(const uint2*)(xp + xb3 + xstep);

    const uint hstep = KP * 16;
    const uint hob = (uint)(((size_t)bt * TCH) * KP + myu) * 16 + r0;

    uint2 hp; hp.x = 0u; hp.y = 0u;

    for (int tt = 0; tt < TCH; tt += 2) {
        RSTEP(pA, tt)
        RSTEP(pB, tt + 1)
    }

    *(f32x4*)(cstate + coff) = c;
    *(uint2*)(hstate + ((size_t)bt * KP + myu) * 16 + r0) = hp;
}

// ================= fused mega-dispatch =================
// blocks 0-15: rec2(ch2)
// blocks 16-31: rec1(ch1) -> h1g, then FUSED dense2(ch1) for own bt -> xp2w
// blocks 32-287: dense1(chd1) rider -> xp1w
__global__ __launch_bounds__(512) void k_mega_f(
    const int rec2_on, const h16* __restrict__ Uf2, const h16* __restrict__ xp2r,
    float* __restrict__ c2, h16* __restrict__ hs2, const int ch2,
    const int rec1_on, const h16* __restrict__ Uf1, const h16* __restrict__ xp1r,
    h16* __restrict__ h1g, float* __restrict__ c1, h16* __restrict__ hs1, const int ch1,
    const h16* __restrict__ w2f, const float* __restrict__ b2, h16* __restrict__ xp2w,
    const int d1_on, const float* __restrict__ x, const h16* __restrict__ w1f,
    const float* __restrict__ b1, const int chd1, h16* __restrict__ xp1w)
{
    const int bid = blockIdx.x, j = threadIdx.x;
    if (bid < 16) {
        if (rec2_on) rec_body(Uf2, xp2r, (h16*)nullptr, 0, c2, hs2, ch2, bid, j);
    } else if (bid < 32) {
        if (rec1_on) {
            const int bt = bid - 16;
            rec_body(Uf1, xp1r, h1g, 1, c1, hs1, ch1, bt, j);
            __syncthreads();   // drain hout stores; same-block global RAW safe (L1 write-invalidate)
            dense_body<1>((const float*)nullptr, h1g, w2f, b2, H2_, 0, xp2w, bt, j, TCH);
        }
    } else {
        if (d1_on) dense_body<0>(x, (const h16*)nullptr, w1f, b1, H1_, chd1, xp1w, bid - 32, j, 4);
    }
}

// ================= head =================
__global__ void k_head(const h16* __restrict__ h2s, const float* __restrict__ Wd,
                       const float* __restrict__ bd, float* __restrict__ out)
{
    __shared__ float lg[OUT_];
    const int b = blockIdx.x, j = threadIdx.x;
    const int bt = b >> 4, r = b & 15;
    if (j < OUT_) {
        float acc = bd[j];
        for (int u = 0; u < H2_; ++u)
            acc += (float)h2s[((size_t)bt * KP + u) * 16 + r] * Wd[u * OUT_ + j];
        lg[j] = acc;
    }
    __syncthreads();
    if (j < OUT_) {
        float m = -1e30f;
        for (int k = 0; k < OUT_; ++k) m = fmaxf(m, lg[k]);
        float s = 0.0f;
        for (int k = 0; k < OUT_; ++k) s += expf(lg[k] - m);
        out[b * OUT_ + j] = expf(lg[j] - m) / s;
    }
}

// ================= R9 fallback (known-good) =================
#define G1_  400
#define G2_  512
#define FBTC 32
#define FB_XP1  0
#define FB_XP2  0
#define FB_WQ   51200
#define FB_XS   134400
#define FB_W2Q  32768
#define FB_H1C  139264
#define FB_U2Q  32768
#define FB_ZBUF 160000
#define FB_H1PK 162048
#define FB_H2PK 162256
#define FB_H2F  162512
#define FB_LDS  163328

__device__ __forceinline__ float fd2(uint wv, uint hv, float cc) {
#if __has_builtin(__builtin_amdgcn_fdot2)
    return __builtin_amdgcn_fdot2(__builtin_bit_cast(h16x2, wv),
                                  __builtin_bit_cast(h16x2, hv), cc, false);
#else
    h16x2 a = __builtin_bit_cast(h16x2, wv), b = __builtin_bit_cast(h16x2, hv);
    return cc + (float)a.x * (float)b.x + (float)a.y * (float)b.y;
#endif
}

__device__ __forceinline__ void stage_quads(const float* __restrict__ P, const int G,
                                            const int NQ, const int KREAL,
                                            char* dst, const int j)
{
    if (j < G) {
        for (int q = 0; q < NQ; ++q) {
            float f[8];
            #pragma unroll
            for (int r = 0; r < 8; ++r) {
                const int k = 8 * q + r;
                f[r] = (k < KREAL) ? P[(size_t)k * G + j] : 0.0f;
            }
            uint4 u;
            u.x = pk2(f[0], f[1]); u.y = pk2(f[2], f[3]);
            u.z = pk2(f[4], f[5]); u.w = pk2(f[6], f[7]);
            *(uint4*)(dst + (size_t)(q * G + j) * 16) = u;
        }
    }
}

__global__ __launch_bounds__(512) void lstm_fallback(
    const float* __restrict__ x,
    const float* __restrict__ W1, const float* __restrict__ U1, const float* __restrict__ b1,
    const float* __restrict__ W2, const float* __restrict__ U2, const float* __restrict__ b2,
    const float* __restrict__ Wd, const float* __restrict__ bd,
    float* __restrict__ out)
{
    __shared__ uint4 smem4[FB_LDS / 16];
    char* sm = (char*)smem4;
    const int b = blockIdx.x;
    const int j = threadIdx.x;
    float c1 = 0.0f, c2 = 0.0f;

    const uint u2r0 = pk2(U2[120 * G2_ + j], U2[121 * G2_ + j]);
    const uint u2r1 = pk2(U2[122 * G2_ + j], U2[123 * G2_ + j]);
    const uint u2r2 = pk2(U2[124 * G2_ + j], U2[125 * G2_ + j]);
    const uint u2r3 = pk2(U2[126 * G2_ + j], U2[127 * G2_ + j]);

    if (j < 52) *(uint*)(sm + FB_H1PK + 4 * j) = 0u;
    if (j < 64) *(uint*)(sm + FB_H2PK + 4 * j) = 0u;
    __syncthreads();

    const float* xrow = x + (size_t)b * T_ * F_;
    for (int ch = 0; ch < T_ / FBTC; ++ch) {
        stage_quads(W1, G1_, 8, 64, sm + FB_WQ, j);
        #pragma unroll
        for (int r = 0; r < 2; ++r) {
            int v = r * 512 + j;
            float2 xv = *(const float2*)(xrow + ch * (FBTC * F_) + 2 * v);
            *(uint*)(sm + FB_XS + 4 * v) = pk2(xv.x, xv.y);
        }
        __syncthreads();
        if (j < G1_) {
            const float bj = b1[j];
            const uint4* WQ = (const uint4*)(sm + FB_WQ);
            for (int t = 0; t < FBTC; ++t) {
                const uint4* XQ = (const uint4*)(sm + FB_XS + t * 128);
                float a0 = bj, a1 = 0.f, a2 = 0.f, a3 = 0.f;
                #pragma unroll
                for (int q = 0; q < 8; ++q) {
                    uint4 wq = WQ[q * G1_ + j]; uint4 hq = XQ[q];
                    a0 = fd2(wq.x, hq.x, a0); a1 = fd2(wq.y, hq.y, a1);
                    a2 = fd2(wq.z, hq.z, a2); a3 = fd2(wq.w, hq.w, a3);
                }
                *(float*)(sm + FB_XP1 + 4 * (t * G1_ + j)) = (a0 + a1) + (a2 + a3);
            }
        }
        __syncthreads();
        stage_quads(U1, G1_, 13, H1_, sm + FB_WQ, j);
        __syncthreads();
        for (int t = 0; t < FBTC; ++t) {
            if (j < G1_) {
                const uint4* WQ = (const uint4*)(sm + FB_WQ);
                const uint4* HP = (const uint4*)(sm + FB_H1PK);
                float a0 = *(const float*)(sm + FB_XP1 + 4 * (t * G1_ + j));
                float a1 = 0.f, a2 = 0.f, a3 = 0.f;
                #pragma unroll
                for (int q = 0; q < 13; ++q) {
                    uint4 wq = WQ[q * G1_ + j]; uint4 hq = HP[q];
                    a0 = fd2(wq.x, hq.x, a0); a1 = fd2(wq.y, hq.y, a1);
                    a2 = fd2(wq.z, hq.z, a2); a3 = fd2(wq.w, hq.w, a3);
                }
                *(float*)(sm + FB_ZBUF + 4 * j) = (a0 + a1) + (a2 + a3);
            }
            __syncthreads();
            if (j < H1_) {
                const float* zb = (const float*)(sm + FB_ZBUF);
                float ig = sigm(zb[j]);
                float fg = sigm(zb[H1_ + j]);
                float gg = fmaxf(zb[2 * H1_ + j], 0.0f);
                float og = sigm(zb[3 * H1_ + j]);
                c1 = fg * c1 + ig * gg;
                float h = og * fmaxf(c1, 0.0f);
                h16 hh = (h16)h;
                *(h16*)(sm + FB_H1PK + 2 * j) = hh;
                *(h16*)(sm + FB_H1C + t * 208 + 2 * j) = hh;
            }
            __syncthreads();
        }
        stage_quads(W2, G2_, 13, H1_, sm + FB_W2Q, j);
        __syncthreads();
        {
            const float bj = b2[j];
            const uint4* WQ = (const uint4*)(sm + FB_W2Q);
            for (int t = 0; t < FBTC; ++t) {
                const uint4* HC = (const uint4*)(sm + FB_H1C + t * 208);
                float a0 = bj, a1 = 0.f, a2 = 0.f, a3 = 0.f;
                #pragma unroll
                for (int q = 0; q < 13; ++q) {
                    uint4 wq = WQ[q * G2_ + j]; uint4 hq = HC[q];
                    a0 = fd2(wq.x, hq.x, a0); a1 = fd2(wq.y, hq.y, a1);
                    a2 = fd2(wq.z, hq.z, a2); a3 = fd2(wq.w, hq.w, a3);
                }
                *(h16*)(sm + FB_XP2 + 2 * (t * G2_ + j)) = (h16)((a0 + a1) + (a2 + a3));
            }
        }
        __syncthreads();
        stage_quads(U2, G2_, 15, 120, sm + FB_U2Q, j);
        __syncthreads();
        for (int t = 0; t < FBTC; ++t) {
            {
                const uint4* WQ = (const uint4*)(sm + FB_U2Q);
                const uint4* HP = (const uint4*)(sm + FB_H2PK);
                float a0 = (float)*(const h16*)(sm + FB_XP2 + 2 * (t * G2_ + j));
                float a1 = 0.f, a2 = 0.f, a3 = 0.f;
                #pragma unroll
                for (int q = 0; q < 15; ++q) {
                    uint4 wq = WQ[q * G2_ + j]; uint4 hq = HP[q];
                    a0 = fd2(wq.x, hq.x, a0); a1 = fd2(wq.y, hq.y, a1);
                    a2 = fd2(wq.z, hq.z, a2); a3 = fd2(wq.w, hq.w, a3);
                }
                uint4 hp15 = ((const uint4*)(sm + FB_H2PK))[15];
                a0 = fd2(u2r0, hp15.x, a0); a1 = fd2(u2r1, hp15.y, a1);
                a2 = fd2(u2r2, hp15.z, a2); a3 = fd2(u2r3, hp15.w, a3);
                *(float*)(sm + FB_ZBUF + 4 * j) = (a0 + a1) + (a2 + a3);
            }
            __syncthreads();
            if (j < H2_) {
                const float* zb = (const float*)(sm + FB_ZBUF);
                float ig = sigm(zb[j]);
                float fg = sigm(zb[H2_ + j]);
                float gg = fmaxf(zb[2 * H2_ + j], 0.0f);
                float og = sigm(zb[3 * H2_ + j]);
                c2 = fg * c2 + ig * gg;
                float h = og * fmaxf(c2, 0.0f);
                *(h16*)(sm + FB_H2PK + 2 * j) = (h16)h;
                *(float*)(sm + FB_H2F + 4 * j) = h;
            }
            __syncthreads();
        }
    }
    if (j < OUT_) {
        const float* h2 = (const float*)(sm + FB_H2F);
        float acc = bd[j];
        #pragma unroll
        for (int k = 0; k < H2_; ++k) acc += h2[k] * Wd[k * OUT_ + j];
        *(float*)(sm + FB_ZBUF + 4 * j) = acc;
    }
    __syncthreads();
    if (j < OUT_) {
        const float* zb = (const float*)(sm + FB_ZBUF);
        float m = -1e30f;
        for (int k = 0; k < OUT_; ++k) m = fmaxf(m, zb[k]);
        float s = 0.0f;
        for (int k = 0; k < OUT_; ++k) s += expf(zb[k] - m);
        out[b * OUT_ + j] = expf(zb[j] - m) / s;
    }
}

// ================= launcher =================
extern "C" void kernel_launch(void* const* d_in, const int* in_sizes, int n_in,
                              void* d_out, int out_size, void* d_ws, size_t ws_size,
                              hipStream_t stream) {
    const float* x  = (const float*)d_in[0];
    const float* W1 = (const float*)d_in[1];
    const float* U1 = (const float*)d_in[2];
    const float* b1 = (const float*)d_in[3];
    const float* W2 = (const float*)d_in[4];
    const float* U2 = (const float*)d_in[5];
    const float* b2 = (const float*)d_in[6];
    const float* Wd = (const float*)d_in[7];
    const float* bd = (const float*)d_in[8];
    float* out = (float*)d_out;

    if (ws_size >= WS_A) {
        char* ws = (char*)d_ws;
        h16* xp1[2] = { (h16*)(ws + A_XP1A), (h16*)(ws + A_XP1B) };
        h16* xp2[2] = { (h16*)(ws + A_XP2A), (h16*)(ws + A_XP2B) };
        h16*   h1g = (h16*)(ws + A_H1G);
        float* c1  = (float*)(ws + A_C1);
        float* c2  = (float*)(ws + A_C2);
        h16*   hs1 = (h16*)(ws + A_H1S);
        h16*   hs2 = (h16*)(ws + A_H2S);
        h16*   u1f = (h16*)(ws + A_U1F);
        h16*   u2f = (h16*)(ws + A_U2F);
        h16*   w1f = (h16*)(ws + A_W1F);
        h16*   w2f = (h16*)(ws + A_W2F);

        k_prepack4<<<32, 512, 0, stream>>>(U1, U2, W1, W2, u1f, u2f, w1f, w2f);
        k_dense<0><<<256, 512, 0, stream>>>(x, (const h16*)nullptr, w1f, b1, H1_, 0, xp1[0]);
        // prologue: rec1(0)+fused dense2(0) -> xp2[0]; rider dense1(1) -> xp1[1]
        k_mega_f<<<288, 512, 0, stream>>>(
            0, u2f, (const h16*)nullptr, c2, hs2, 0,
            1, u1f, xp1[0], h1g, c1, hs1, 0,
            w2f, b2, xp2[0],
            1, x, w1f, b1, 1, xp1[1]);
        for (int ch = 0; ch < NCH; ++ch) {
            const int r1on = (ch + 1 < NCH);
            const int d1on = (ch + 2 < NCH);
            k_mega_f<<<288, 512, 0, stream>>>(
                1, u2f, xp2[ch & 1], c2, hs2, ch,
                r1on, u1f, xp1[(ch + 1) & 1], h1g, c1, hs1, ch + 1,
                w2f, b2, xp2[(ch + 1) & 1],
                d1on, x, w1f, b1, ch + 2, xp1[ch & 1]);
        }
        k_head<<<256, 64, 0, stream>>>(hs2, Wd, bd, out);
    } else {
        lstm_fallback<<<B_, 512, 0, stream>>>(x, W1, U1, b1, W2, U2, b2, Wd, bd, out);
    }
}

// Round 20
// 777.358 us; speedup vs baseline: 1.5002x; 1.5002x over previous
//
#include <hip/hip_runtime.h>
#include <math.h>

// Problem dims
#define B_   256
#define T_   512
#define F_   64
#define H1_  100
#define H2_  128
#define OUT_ 19
#define TCH  64             // timesteps per chunk (pipeline stage)
#define NCH  (T_/TCH)       // 8 chunks
#define NPC  512            // padded+permuted gate columns (both layers)
#define KP   128            // padded K (units) for both layers

typedef unsigned int uint;
typedef _Float16 h16;
typedef __attribute__((ext_vector_type(2))) _Float16 h16x2;
typedef __attribute__((ext_vector_type(8))) _Float16 f16x8;
typedef __attribute__((ext_vector_type(4))) float f32x4;

// ---- workspace layout (bytes) ----
#define XPW_BYTES (16ull*TCH*NPC*16*2)     // 16,777,216 per xp buffer
#define H1G_BYTES (16ull*TCH*KP*16*2)      // 4,194,304 per h1g buffer
#define CST_BYTES (16ull*KP*16*4)          // 131,072
#define HST_BYTES (16ull*KP*16*2)          // 65,536
#define UF_BYTES  (128ull*64*8*2)          // 131,072 per packed weight buffer

// TIER A (R18 schedule + prepacked dense weights): ~76.4 MB
#define A_XP1A  0ull
#define A_XP1B  (A_XP1A + XPW_BYTES)
#define A_XP2A  (A_XP1B + XPW_BYTES)
#define A_XP2B  (A_XP2A + XPW_BYTES)
#define A_H1GA  (A_XP2B + XPW_BYTES)
#define A_H1GB  (A_H1GA + H1G_BYTES)
#define A_C1    (A_H1GB + H1G_BYTES)
#define A_C2    (A_C1   + CST_BYTES)
#define A_H1S   (A_C2   + CST_BYTES)
#define A_H2S   (A_H1S  + HST_BYTES)
#define A_U1F   (A_H2S  + HST_BYTES)
#define A_U2F   (A_U1F  + UF_BYTES)
#define A_W1F   (A_U2F  + UF_BYTES)
#define A_W2F   (A_W1F  + UF_BYTES)
#define WS_A    (A_W2F  + UF_BYTES)        // ~76.4 MB

__device__ __forceinline__ float sigm(float x) { return 1.0f / (1.0f + __expf(-x)); }

__device__ __forceinline__ uint pk2(float a, float b) {
    h16x2 h; h.x = (h16)a; h.y = (h16)b;
    return __builtin_bit_cast(uint, h);
}

__device__ __forceinline__ f32x4 mfma16(f16x8 a, f16x8 b, f32x4 c) {
    return __builtin_amdgcn_mfma_f32_16x16x32_f16(a, b, c, 0, 0, 0);
}

__device__ __forceinline__ f32x4 up4(uint2 v) {
    h16x2 a = __builtin_bit_cast(h16x2, v.x);
    h16x2 b = __builtin_bit_cast(h16x2, v.y);
    f32x4 r; r[0] = (float)a.x; r[1] = (float)a.y; r[2] = (float)b.x; r[3] = (float)b.y;
    return r;
}

// lgkm-only barrier (T4): orders LDS h-exchange without draining vmcnt.
__device__ __forceinline__ void bar_lgkm() {
    asm volatile("s_waitcnt lgkmcnt(0)" ::: "memory");
    __builtin_amdgcn_sched_barrier(0);
    __builtin_amdgcn_s_barrier();
    __builtin_amdgcn_sched_barrier(0);
}

// Strided B-fragment gather with gate-column permutation (prepack + fallback only).
__device__ __forceinline__ f16x8 load_bfrag(const float* __restrict__ P, int H, int OG,
                                            int Kreal, int ubase, int g, int q, int lane) {
    const int u  = ubase + (lane & 15);
    const int k0 = q * 32 + (lane >> 4) * 8;
    const int col = g * H + u;
    float f[8];
    #pragma unroll
    for (int e = 0; e < 8; ++e) {
        const int k = k0 + e;
        f[e] = (u < H && k < Kreal) ? P[(size_t)k * OG + col] : 0.0f;
    }
    uint4 r;
    r.x = pk2(f[0], f[1]); r.y = pk2(f[2], f[3]);
    r.z = pk2(f[4], f[5]); r.w = pk2(f[6], f[7]);
    return __builtin_bit_cast(f16x8, r);
}

// ================= weight prepack (runs once): U1,U2,W1,W2 =================
// Fragment (w,g,q) of lane l at D[(((w*4+g)*4+q)*64 + l)*8 .. +8)
__global__ __launch_bounds__(512) void k_prepack4(
    const float* __restrict__ U1, const float* __restrict__ U2,
    const float* __restrict__ W1, const float* __restrict__ W2,
    h16* __restrict__ u1f, h16* __restrict__ u2f,
    h16* __restrict__ w1f, h16* __restrict__ w2f)
{
    const int w = blockIdx.x & 7;
    const int which = blockIdx.x >> 3;   // 0:U1 1:U2 2:W1 3:W2
    const float* P; int H, K, KF; h16* D;
    if (which == 0)      { P = U1; H = H1_; K = H1_; KF = 4; D = u1f; }
    else if (which == 1) { P = U2; H = H2_; K = H2_; KF = 4; D = u2f; }
    else if (which == 2) { P = W1; H = H1_; K = 64;  KF = 2; D = w1f; }
    else                 { P = W2; H = H2_; K = H1_; KF = 4; D = w2f; }
    const int lane = threadIdx.x & 63;
    #pragma unroll
    for (int it = 0; it < 2; ++it) {
        const int combo = it * 8 + (threadIdx.x >> 6);
        const int g = combo >> 2, q = combo & 3;
        if (q < KF) {
            f16x8 fr = load_bfrag(P, H, 4 * H, K, w * 16, g, q, lane);
            *(f16x8*)(D + (size_t)(((w * 4 + g) * 4 + q) * 64 + lane) * 8) = fr;
        }
    }
}

// ================= dense pre-projection body (prepacked weights) =================
template<int MODE, int NIT>
__device__ __forceinline__ void dense_body(
    const float* __restrict__ Af, const h16* __restrict__ Ah,
    const h16* __restrict__ Wf, const float* __restrict__ bias,
    const int H, const int ch, h16* __restrict__ xp,
    const int bid, const int j)
{
    const int lane = j & 63, w = j >> 6;
    const int KF = MODE ? 4 : 2;

    f16x8 bf[4][4];
    #pragma unroll
    for (int g = 0; g < 4; ++g)
        #pragma unroll
        for (int q = 0; q < 4; ++q)
            if (q < KF)
                bf[g][q] = *(const f16x8*)(Wf + (size_t)(((w * 4 + g) * 4 + q) * 64 + lane) * 8);

    float bv[4];
    #pragma unroll
    for (int g = 0; g < 4; ++g) {
        const int u = w * 16 + (lane & 15);
        bv[g] = (u < H) ? bias[g * H + u] : 0.0f;
    }

    const int ci = lane & 15, hi = lane >> 4;
    #pragma unroll
    for (int it = 0; it < NIT; ++it) {
        const int m = bid * NIT + it;
        const int bt = m / TCH, tc = m % TCH;

        f16x8 af[4];
        if (MODE == 0) {
            const int b = bt * 16 + ci;
            const int t = ch * TCH + tc;
            #pragma unroll
            for (int q = 0; q < 2; ++q) {
                const int k0 = q * 32 + hi * 8;
                const float* p = Af + ((size_t)b * T_ + t) * F_ + k0;
                float4 x0 = *(const float4*)p;
                float4 x1 = *(const float4*)(p + 4);
                uint4 r;
                r.x = pk2(x0.x, x0.y); r.y = pk2(x0.z, x0.w);
                r.z = pk2(x1.x, x1.y); r.w = pk2(x1.z, x1.w);
                af[q] = __builtin_bit_cast(f16x8, r);
            }
        } else {
            #pragma unroll
            for (int q = 0; q < 4; ++q) {
                const int k0 = q * 32 + hi * 8;
                const size_t base = ((size_t)(bt * TCH + tc) * KP + k0) * 16 + ci;
                f16x8 a;
                #pragma unroll
                for (int e = 0; e < 8; ++e) a[e] = Ah[base + (size_t)e * 16];
                af[q] = a;
            }
        }

        f32x4 acc[4];
        #pragma unroll
        for (int g = 0; g < 4; ++g) { acc[g][0]=bv[g]; acc[g][1]=bv[g]; acc[g][2]=bv[g]; acc[g][3]=bv[g]; }
        #pragma unroll
        for (int g = 0; g < 4; ++g)
            #pragma unroll
            for (int q = 0; q < 4; ++q)
                if (q < KF) acc[g] = mfma16(af[q], bf[g][q], acc[g]);

        #pragma unroll
        for (int g = 0; g < 4; ++g) {
            const int c = (w * 4 + g) * 16 + ci;
            const size_t o = ((size_t)(bt * TCH + tc) * NPC + c) * 16 + hi * 4;
            uint2 s;
            s.x = pk2(acc[g][0], acc[g][1]);
            s.y = pk2(acc[g][2], acc[g][3]);
            *(uint2*)(xp + o) = s;
        }
    }
}

template<int MODE>
__global__ __launch_bounds__(512) void k_dense(
    const float* __restrict__ Af, const h16* __restrict__ Ah,
    const h16* __restrict__ Wf, const float* __restrict__ bias,
    const int H, const int ch, h16* __restrict__ xp)
{
    dense_body<MODE, 4>(Af, Ah, Wf, bias, H, ch, xp, blockIdx.x, threadIdx.x);
}

// ================= recurrence body (R17, unchanged) =================
#define LF(G,Q) f16x8 wf##G##Q = *(const f16x8*)(Uf + (size_t)(((w*4+G)*4+Q)*64 + lane)*8);

#define RSTEP(Pn, tcur)                                                          \
    {                                                                            \
        const int t_ = (tcur);                                                   \
        const h16* hb = &hbuf[t_ & 1][0][0];                                     \
        f16x8 a0 = *(const f16x8*)(hb + ci * 136 + 0  + hi * 8);                 \
        f16x8 a1 = *(const f16x8*)(hb + ci * 136 + 32 + hi * 8);                 \
        f16x8 a2 = *(const f16x8*)(hb + ci * 136 + 64 + hi * 8);                 \
        f16x8 a3 = *(const f16x8*)(hb + ci * 136 + 96 + hi * 8);                 \
        f32x4 z0 = up4(Pn##0), z1 = up4(Pn##1), z2 = up4(Pn##2), z3 = up4(Pn##3);\
        const uint to_ = (uint)((t_ + 2 < TCH) ? t_ + 2 : t_) * xstep;           \
        Pn##0 = *(const uint2*)(xp + xb0 + to_);                                 \
        Pn##1 = *(const uint2*)(xp + xb1 + to_);                                 \
        Pn##2 = *(const uint2*)(xp + xb2 + to_);                                 \
        Pn##3 = *(const uint2*)(xp + xb3 + to_);                                 \
        z0 = mfma16(a0, wf00, z0); z0 = mfma16(a1, wf01, z0);                    \
        z0 = mfma16(a2, wf02, z0); z0 = mfma16(a3, wf03, z0);                    \
        z1 = mfma16(a0, wf10, z1); z1 = mfma16(a1, wf11, z1);                    \
        z1 = mfma16(a2, wf12, z1); z1 = mfma16(a3, wf13, z1);                    \
        z2 = mfma16(a0, wf20, z2); z2 = mfma16(a1, wf21, z2);                    \
        z2 = mfma16(a2, wf22, z2); z2 = mfma16(a3, wf23, z2);                    \
        z3 = mfma16(a0, wf30, z3); z3 = mfma16(a1, wf31, z3);                    \
        z3 = mfma16(a2, wf32, z3); z3 = mfma16(a3, wf33, z3);                    \
        f32x4 hv;                                                                \
        _Pragma("unroll")                                                        \
        for (int i = 0; i < 4; ++i) {                                            \
            float ig = sigm(z0[i]);                                              \
            float fg = sigm(z1[i]);                                              \
            float gg = fmaxf(z2[i], 0.0f);                                       \
            float og = sigm(z3[i]);                                              \
            c[i] = fg * c[i] + ig * gg;                                          \
            hv[i] = og * fmaxf(c[i], 0.0f);                                      \
        }                                                                        \
        h16 h0 = (h16)hv[0], h1 = (h16)hv[1], h2 = (h16)hv[2], h3 = (h16)hv[3]; \
        const int nb_ = (t_ & 1) ^ 1;                                            \
        hbuf[nb_][r0 + 0][myu] = h0;                                             \
        hbuf[nb_][r0 + 1][myu] = h1;                                             \
        hbuf[nb_][r0 + 2][myu] = h2;                                             \
        hbuf[nb_][r0 + 3][myu] = h3;                                             \
        h16x2 p01_; p01_.x = h0; p01_.y = h1;                                    \
        h16x2 p23_; p23_.x = h2; p23_.y = h3;                                    \
        hp.x = __builtin_bit_cast(uint, p01_);                                   \
        hp.y = __builtin_bit_cast(uint, p23_);                                   \
        if (do_hout) *(uint2*)(hout + hob + (uint)t_ * hstep) = hp;              \
        bar_lgkm();                                                              \
    }

__device__ __forceinline__ void rec_body(
    const h16* __restrict__ Uf,
    const h16* __restrict__ xp, h16* __restrict__ hout, const int do_hout,
    float* __restrict__ cstate, h16* __restrict__ hstate, const int ch,
    const int bt, const int j)
{
    __shared__ h16 hbuf[2][16][136];
    const int lane = j & 63, w = j >> 6;
    const int ci = lane & 15, hi = lane >> 4;
    const int myu = w * 16 + ci;
    const int r0 = hi * 4;

    LF(0,0) LF(0,1) LF(0,2) LF(0,3)
    LF(1,0) LF(1,1) LF(1,2) LF(1,3)
    LF(2,0) LF(2,1) LF(2,2) LF(2,3)
    LF(3,0) LF(3,1) LF(3,2) LF(3,3)

    {
        const int u = j & 127, rr = (j >> 7) * 4;
        #pragma unroll
        for (int i = 0; i < 4; ++i) {
            h16 v = (h16)0.0f;
            if (ch != 0) v = hstate[((size_t)bt * KP + u) * 16 + rr + i];
            hbuf[0][rr + i][u] = v;
        }
    }
    f32x4 c;
    const size_t coff = ((size_t)bt * KP + myu) * 16 + r0;
    if (ch == 0) { c[0]=0.f; c[1]=0.f; c[2]=0.f; c[3]=0.f; }
    else         { c = *(const f32x4*)(cstate + coff); }
    __syncthreads();

    const uint xstep = NPC * 16;
    const uint xb0 = (uint)(((size_t)bt * TCH) * NPC + (w * 64 + ci)) * 16 + r0;
    const uint xb1 = xb0 + 16 * 16, xb2 = xb0 + 32 * 16, xb3 = xb0 + 48 * 16;

    uint2 pA0 = *(const uint2*)(xp + xb0);
    uint2 pA1 = *(const uint2*)(xp + xb1);
    uint2 pA2 = *(const uint2*)(xp + xb2);
    uint2 pA3 = *(const uint2*)(xp + xb3);
    uint2 pB0 = *(const uint2*)(xp + xb0 + xstep);
    uint2 pB1 = *(const uint2*)(xp + xb1 + xstep);
    uint2 pB2 = *(const uint2*)(xp + xb2 + xstep);
    uint2 pB3 = *(const uint2*)(xp + xb3 + xstep);

    const uint hstep = KP * 16;
    const uint hob = (uint)(((size_t)bt * TCH) * KP + myu) * 16 + r0;

    uint2 hp; hp.x = 0u; hp.y = 0u;

    for (int tt = 0; tt < TCH; tt += 2) {
        RSTEP(pA, tt)
        RSTEP(pB, tt + 1)
    }

    *(f32x4*)(cstate + coff) = c;
    *(uint2*)(hstate + ((size_t)bt * KP + myu) * 16 + r0) = hp;
}

// ================= unified mega-dispatch (R18 structure, prepacked weights) ====
// blocks 0-15: rec2 | 16-31: rec1 | 32-287: dense2 rider | 288-543: dense1 rider
__global__ __launch_bounds__(512) void k_mega(
    const int rec2_on, const h16* __restrict__ Uf2, const h16* __restrict__ xp2r,
    float* __restrict__ c2, h16* __restrict__ hs2, const int ch2,
    const int rec1_on, const h16* __restrict__ Uf1, const h16* __restrict__ xp1r,
    h16* __restrict__ h1gw, float* __restrict__ c1, h16* __restrict__ hs1, const int ch1,
    const int d2_on, const h16* __restrict__ h1gr, const h16* __restrict__ w2f,
    const float* __restrict__ b2, h16* __restrict__ xp2w,
    const int d1_on, const float* __restrict__ x, const h16* __restrict__ w1f,
    const float* __restrict__ b1, const int chd1, h16* __restrict__ xp1w)
{
    const int bid = blockIdx.x, j = threadIdx.x;
    if (bid < 16) {
        if (rec2_on) rec_body(Uf2, xp2r, (h16*)nullptr, 0, c2, hs2, ch2, bid, j);
    } else if (bid < 32) {
        if (rec1_on) rec_body(Uf1, xp1r, h1gw, 1, c1, hs1, ch1, bid - 16, j);
    } else if (bid < 288) {
        if (d2_on) dense_body<1, 4>((const float*)nullptr, h1gr, w2f, b2, H2_, 0, xp2w, bid - 32, j);
    } else {
        if (d1_on) dense_body<0, 4>(x, (const h16*)nullptr, w1f, b1, H1_, chd1, xp1w, bid - 288, j);
    }
}

// ================= head =================
__global__ void k_head(const h16* __restrict__ h2s, const float* __restrict__ Wd,
                       const float* __restrict__ bd, float* __restrict__ out)
{
    __shared__ float lg[OUT_];
    const int b = blockIdx.x, j = threadIdx.x;
    const int bt = b >> 4, r = b & 15;
    if (j < OUT_) {
        float acc = bd[j];
        for (int u = 0; u < H2_; ++u)
            acc += (float)h2s[((size_t)bt * KP + u) * 16 + r] * Wd[u * OUT_ + j];
        lg[j] = acc;
    }
    __syncthreads();
    if (j < OUT_) {
        float m = -1e30f;
        for (int k = 0; k < OUT_; ++k) m = fmaxf(m, lg[k]);
        float s = 0.0f;
        for (int k = 0; k < OUT_; ++k) s += expf(lg[k] - m);
        out[b * OUT_ + j] = expf(lg[j] - m) / s;
    }
}

// ================= R9 fallback (known-good) =================
#define G1_  400
#define G2_  512
#define FBTC 32
#define FB_XP1  0
#define FB_XP2  0
#define FB_WQ   51200
#define FB_XS   134400
#define FB_W2Q  32768
#define FB_H1C  139264
#define FB_U2Q  32768
#define FB_ZBUF 160000
#define FB_H1PK 162048
#define FB_H2PK 162256
#define FB_H2F  162512
#define FB_LDS  163328

__device__ __forceinline__ float fd2(uint wv, uint hv, float cc) {
#if __has_builtin(__builtin_amdgcn_fdot2)
    return __builtin_amdgcn_fdot2(__builtin_bit_cast(h16x2, wv),
                                  __builtin_bit_cast(h16x2, hv), cc, false);
#else
    h16x2 a = __builtin_bit_cast(h16x2, wv), b = __builtin_bit_cast(h16x2, hv);
    return cc + (float)a.x * (float)b.x + (float)a.y * (float)b.y;
#endif
}

__device__ __forceinline__ void stage_quads(const float* __restrict__ P, const int G,
                                            const int NQ, const int KREAL,
                                            char* dst, const int j)
{
    if (j < G) {
        for (int q = 0; q < NQ; ++q) {
            float f[8];
            #pragma unroll
            for (int r = 0; r < 8; ++r) {
                const int k = 8 * q + r;
                f[r] = (k < KREAL) ? P[(size_t)k * G + j] : 0.0f;
            }
            uint4 u;
            u.x = pk2(f[0], f[1]); u.y = pk2(f[2], f[3]);
            u.z = pk2(f[4], f[5]); u.w = pk2(f[6], f[7]);
            *(uint4*)(dst + (size_t)(q * G + j) * 16) = u;
        }
    }
}

__global__ __launch_bounds__(512) void lstm_fallback(
    const float* __restrict__ x,
    const float* __restrict__ W1, const float* __restrict__ U1, const float* __restrict__ b1,
    const float* __restrict__ W2, const float* __restrict__ U2, const float* __restrict__ b2,
    const float* __restrict__ Wd, const float* __restrict__ bd,
    float* __restrict__ out)
{
    __shared__ uint4 smem4[FB_LDS / 16];
    char* sm = (char*)smem4;
    const int b = blockIdx.x;
    const int j = threadIdx.x;
    float c1 = 0.0f, c2 = 0.0f;

    const uint u2r0 = pk2(U2[120 * G2_ + j], U2[121 * G2_ + j]);
    const uint u2r1 = pk2(U2[122 * G2_ + j], U2[123 * G2_ + j]);
    const uint u2r2 = pk2(U2[124 * G2_ + j], U2[125 * G2_ + j]);
    const uint u2r3 = pk2(U2[126 * G2_ + j], U2[127 * G2_ + j]);

    if (j < 52) *(uint*)(sm + FB_H1PK + 4 * j) = 0u;
    if (j < 64) *(uint*)(sm + FB_H2PK + 4 * j) = 0u;
    __syncthreads();

    const float* xrow = x + (size_t)b * T_ * F_;
    for (int ch = 0; ch < T_ / FBTC; ++ch) {
        stage_quads(W1, G1_, 8, 64, sm + FB_WQ, j);
        #pragma unroll
        for (int r = 0; r < 2; ++r) {
            int v = r * 512 + j;
            float2 xv = *(const float2*)(xrow + ch * (FBTC * F_) + 2 * v);
            *(uint*)(sm + FB_XS + 4 * v) = pk2(xv.x, xv.y);
        }
        __syncthreads();
        if (j < G1_) {
            const float bj = b1[j];
            const uint4* WQ = (const uint4*)(sm + FB_WQ);
            for (int t = 0; t < FBTC; ++t) {
                const uint4* XQ = (const uint4*)(sm + FB_XS + t * 128);
                float a0 = bj, a1 = 0.f, a2 = 0.f, a3 = 0.f;
                #pragma unroll
                for (int q = 0; q < 8; ++q) {
                    uint4 wq = WQ[q * G1_ + j]; uint4 hq = XQ[q];
                    a0 = fd2(wq.x, hq.x, a0); a1 = fd2(wq.y, hq.y, a1);
                    a2 = fd2(wq.z, hq.z, a2); a3 = fd2(wq.w, hq.w, a3);
                }
                *(float*)(sm + FB_XP1 + 4 * (t * G1_ + j)) = (a0 + a1) + (a2 + a3);
            }
        }
        __syncthreads();
        stage_quads(U1, G1_, 13, H1_, sm + FB_WQ, j);
        __syncthreads();
        for (int t = 0; t < FBTC; ++t) {
            if (j < G1_) {
                const uint4* WQ = (const uint4*)(sm + FB_WQ);
                const uint4* HP = (const uint4*)(sm + FB_H1PK);
                float a0 = *(const float*)(sm + FB_XP1 + 4 * (t * G1_ + j));
                float a1 = 0.f, a2 = 0.f, a3 = 0.f;
                #pragma unroll
                for (int q = 0; q < 13; ++q) {
                    uint4 wq = WQ[q * G1_ + j]; uint4 hq = HP[q];
                    a0 = fd2(wq.x, hq.x, a0); a1 = fd2(wq.y, hq.y, a1);
                    a2 = fd2(wq.z, hq.z, a2); a3 = fd2(wq.w, hq.w, a3);
                }
                *(float*)(sm + FB_ZBUF + 4 * j) = (a0 + a1) + (a2 + a3);
            }
            __syncthreads();
            if (j < H1_) {
                const float* zb = (const float*)(sm + FB_ZBUF);
                float ig = sigm(zb[j]);
                float fg = sigm(zb[H1_ + j]);
                float gg = fmaxf(zb[2 * H1_ + j], 0.0f);
                float og = sigm(zb[3 * H1_ + j]);
                c1 = fg * c1 + ig * gg;
                float h = og * fmaxf(c1, 0.0f);
                h16 hh = (h16)h;
                *(h16*)(sm + FB_H1PK + 2 * j) = hh;
                *(h16*)(sm + FB_H1C + t * 208 + 2 * j) = hh;
            }
            __syncthreads();
        }
        stage_quads(W2, G2_, 13, H1_, sm + FB_W2Q, j);
        __syncthreads();
        {
            const float bj = b2[j];
            const uint4* WQ = (const uint4*)(sm + FB_W2Q);
            for (int t = 0; t < FBTC; ++t) {
                const uint4* HC = (const uint4*)(sm + FB_H1C + t * 208);
                float a0 = bj, a1 = 0.f, a2 = 0.f, a3 = 0.f;
                #pragma unroll
                for (int q = 0; q < 13; ++q) {
                    uint4 wq = WQ[q * G2_ + j]; uint4 hq = HC[q];
                    a0 = fd2(wq.x, hq.x, a0); a1 = fd2(wq.y, hq.y, a1);
                    a2 = fd2(wq.z, hq.z, a2); a3 = fd2(wq.w, hq.w, a3);
                }
                *(h16*)(sm + FB_XP2 + 2 * (t * G2_ + j)) = (h16)((a0 + a1) + (a2 + a3));
            }
        }
        __syncthreads();
        stage_quads(U2, G2_, 15, 120, sm + FB_U2Q, j);
        __syncthreads();
        for (int t = 0; t < FBTC; ++t) {
            {
                const uint4* WQ = (const uint4*)(sm + FB_U2Q);
                const uint4* HP = (const uint4*)(sm + FB_H2PK);
                float a0 = (float)*(const h16*)(sm + FB_XP2 + 2 * (t * G2_ + j));
                float a1 = 0.f, a2 = 0.f, a3 = 0.f;
                #pragma unroll
                for (int q = 0; q < 15; ++q) {
                    uint4 wq = WQ[q * G2_ + j]; uint4 hq = HP[q];
                    a0 = fd2(wq.x, hq.x, a0); a1 = fd2(wq.y, hq.y, a1);
                    a2 = fd2(wq.z, hq.z, a2); a3 = fd2(wq.w, hq.w, a3);
                }
                uint4 hp15 = ((const uint4*)(sm + FB_H2PK))[15];
                a0 = fd2(u2r0, hp15.x, a0); a1 = fd2(u2r1, hp15.y, a1);
                a2 = fd2(u2r2, hp15.z, a2); a3 = fd2(u2r3, hp15.w, a3);
                *(float*)(sm + FB_ZBUF + 4 * j) = (a0 + a1) + (a2 + a3);
            }
            __syncthreads();
            if (j < H2_) {
                const float* zb = (const float*)(sm + FB_ZBUF);
                float ig = sigm(zb[j]);
                float fg = sigm(zb[H2_ + j]);
                float gg = fmaxf(zb[2 * H2_ + j], 0.0f);
                float og = sigm(zb[3 * H2_ + j]);
                c2 = fg * c2 + ig * gg;
                float h = og * fmaxf(c2, 0.0f);
                *(h16*)(sm + FB_H2PK + 2 * j) = (h16)h;
                *(float*)(sm + FB_H2F + 4 * j) = h;
            }
            __syncthreads();
        }
    }
    if (j < OUT_) {
        const float* h2 = (const float*)(sm + FB_H2F);
        float acc = bd[j];
        #pragma unroll
        for (int k = 0; k < H2_; ++k) acc += h2[k] * Wd[k * OUT_ + j];
        *(float*)(sm + FB_ZBUF + 4 * j) = acc;
    }
    __syncthreads();
    if (j < OUT_) {
        const float* zb = (const float*)(sm + FB_ZBUF);
        float m = -1e30f;
        for (int k = 0; k < OUT_; ++k) m = fmaxf(m, zb[k]);
        float s = 0.0f;
        for (int k = 0; k < OUT_; ++k) s += expf(zb[k] - m);
        out[b * OUT_ + j] = expf(zb[j] - m) / s;
    }
}

// ================= launcher =================
extern "C" void kernel_launch(void* const* d_in, const int* in_sizes, int n_in,
                              void* d_out, int out_size, void* d_ws, size_t ws_size,
                              hipStream_t stream) {
    const float* x  = (const float*)d_in[0];
    const float* W1 = (const float*)d_in[1];
    const float* U1 = (const float*)d_in[2];
    const float* b1 = (const float*)d_in[3];
    const float* W2 = (const float*)d_in[4];
    const float* U2 = (const float*)d_in[5];
    const float* b2 = (const float*)d_in[6];
    const float* Wd = (const float*)d_in[7];
    const float* bd = (const float*)d_in[8];
    float* out = (float*)d_out;

    if (ws_size >= WS_A) {
        char* ws = (char*)d_ws;
        h16* xp1[2] = { (h16*)(ws + A_XP1A), (h16*)(ws + A_XP1B) };
        h16* xp2[2] = { (h16*)(ws + A_XP2A), (h16*)(ws + A_XP2B) };
        h16* h1g[2] = { (h16*)(ws + A_H1GA), (h16*)(ws + A_H1GB) };
        float* c1  = (float*)(ws + A_C1);
        float* c2  = (float*)(ws + A_C2);
        h16*   hs1 = (h16*)(ws + A_H1S);
        h16*   hs2 = (h16*)(ws + A_H2S);
        h16*   u1f = (h16*)(ws + A_U1F);
        h16*   u2f = (h16*)(ws + A_U2F);
        h16*   w1f = (h16*)(ws + A_W1F);
        h16*   w2f = (h16*)(ws + A_W2F);

        k_prepack4<<<32, 512, 0, stream>>>(U1, U2, W1, W2, u1f, u2f, w1f, w2f);
        k_dense<0><<<256, 512, 0, stream>>>(x, (const h16*)nullptr, w1f, b1, H1_, 0, xp1[0]);
        // P-1: rec1(0) -> h1g[0]; rider dense1(1) -> xp1[1]
        k_mega<<<544, 512, 0, stream>>>(
            0, u2f, (const h16*)nullptr, c2, hs2, 0,
            1, u1f, xp1[0], h1g[0], c1, hs1, 0,
            0, (const h16*)nullptr, w2f, b2, (h16*)nullptr,
            1, x, w1f, b1, 1, xp1[1]);
        // P0: rec1(1) -> h1g[1]; riders dense2(0): h1g[0]->xp2[0], dense1(2)->xp1[0]
        k_mega<<<544, 512, 0, stream>>>(
            0, u2f, (const h16*)nullptr, c2, hs2, 0,
            1, u1f, xp1[1], h1g[1], c1, hs1, 1,
            1, h1g[0], w2f, b2, xp2[0],
            1, x, w1f, b1, 2, xp1[0]);
        for (int ch = 0; ch < NCH; ++ch) {
            const int r1on = (ch + 2 < NCH);
            const int d2on = (ch + 1 < NCH);
            const int d1on = (ch + 3 < NCH);
            k_mega<<<544, 512, 0, stream>>>(
                1, u2f, xp2[ch & 1], c2, hs2, ch,
                r1on, u1f, xp1[(ch + 2) & 1], h1g[(ch + 2) & 1], c1, hs1, ch + 2,
                d2on, h1g[(ch + 1) & 1], w2f, b2, xp2[(ch + 1) & 1],
                d1on, x, w1f, b1, ch + 3, xp1[(ch + 3) & 1]);
        }
        k_head<<<256, 64, 0, stream>>>(hs2, Wd, bd, out);
    } else {
        lstm_fallback<<<B_, 512, 0, stream>>>(x, W1, U1, b1, W2, U2, b2, Wd, bd, out);
    }
}

// Round 21
// 748.565 us; speedup vs baseline: 1.5579x; 1.0385x over previous
//
#include <hip/hip_runtime.h>
#include <math.h>

// Problem dims
#define B_   256
#define T_   512
#define F_   64
#define H1_  100
#define H2_  128
#define OUT_ 19
#define TCH  32             // timesteps per chunk (pipeline stage)
#define NCH  (T_/TCH)       // 16 chunks
#define NPC  512            // padded+permuted gate columns (both layers)
#define KP   128            // padded K (units) for both layers

typedef unsigned int uint;
typedef _Float16 h16;
typedef __attribute__((ext_vector_type(2))) _Float16 h16x2;
typedef __attribute__((ext_vector_type(8))) _Float16 f16x8;
typedef __attribute__((ext_vector_type(4))) float f32x4;

// ---- workspace layout (bytes) ----
#define XPW_BYTES (16ull*TCH*NPC*16*2)     // 8,388,608 per xp buffer
#define H1G_BYTES (16ull*TCH*KP*16*2)      // 2,097,152 per h1g buffer
#define CST_BYTES (16ull*KP*16*4)          // 131,072
#define HST_BYTES (16ull*KP*16*2)          // 65,536
#define UF_BYTES  (128ull*64*8*2)          // 131,072 per packed weight buffer

#define A_XP1A  0ull
#define A_XP1B  (A_XP1A + XPW_BYTES)
#define A_XP2A  (A_XP1B + XPW_BYTES)
#define A_XP2B  (A_XP2A + XPW_BYTES)
#define A_H1GA  (A_XP2B + XPW_BYTES)
#define A_H1GB  (A_H1GA + H1G_BYTES)
#define A_C1    (A_H1GB + H1G_BYTES)
#define A_C2    (A_C1   + CST_BYTES)
#define A_H1S   (A_C2   + CST_BYTES)
#define A_H2S   (A_H1S  + HST_BYTES)
#define A_U1F   (A_H2S  + HST_BYTES)
#define A_U2F   (A_U1F  + UF_BYTES)
#define A_W1F   (A_U2F  + UF_BYTES)
#define A_W2F   (A_W1F  + UF_BYTES)
#define WS_A    (A_W2F  + UF_BYTES)        // ~38.6 MB

__device__ __forceinline__ float sigm(float x) { return 1.0f / (1.0f + __expf(-x)); }

__device__ __forceinline__ uint pk2(float a, float b) {
    h16x2 h; h.x = (h16)a; h.y = (h16)b;
    return __builtin_bit_cast(uint, h);
}

__device__ __forceinline__ f32x4 mfma16(f16x8 a, f16x8 b, f32x4 c) {
    return __builtin_amdgcn_mfma_f32_16x16x32_f16(a, b, c, 0, 0, 0);
}

__device__ __forceinline__ f32x4 up4(uint2 v) {
    h16x2 a = __builtin_bit_cast(h16x2, v.x);
    h16x2 b = __builtin_bit_cast(h16x2, v.y);
    f32x4 r; r[0] = (float)a.x; r[1] = (float)a.y; r[2] = (float)b.x; r[3] = (float)b.y;
    return r;
}

// lgkm-only barrier (T4): orders LDS h-exchange without draining vmcnt.
__device__ __forceinline__ void bar_lgkm() {
    asm volatile("s_waitcnt lgkmcnt(0)" ::: "memory");
    __builtin_amdgcn_sched_barrier(0);
    __builtin_amdgcn_s_barrier();
    __builtin_amdgcn_sched_barrier(0);
}

// Strided B-fragment gather with gate-column permutation.
__device__ __forceinline__ f16x8 load_bfrag(const float* __restrict__ P, int H, int OG,
                                            int Kreal, int ubase, int g, int q, int lane) {
    const int u  = ubase + (lane & 15);
    const int k0 = q * 32 + (lane >> 4) * 8;
    const int col = g * H + u;
    float f[8];
    #pragma unroll
    for (int e = 0; e < 8; ++e) {
        const int k = k0 + e;
        f[e] = (u < H && k < Kreal) ? P[(size_t)k * OG + col] : 0.0f;
    }
    uint4 r;
    r.x = pk2(f[0], f[1]); r.y = pk2(f[2], f[3]);
    r.z = pk2(f[4], f[5]); r.w = pk2(f[6], f[7]);
    return __builtin_bit_cast(f16x8, r);
}

// ================= dense core (shared by packed / strided front-ends) =========
template<int MODE, int NIT>
__device__ __forceinline__ void dense_core(
    const float* __restrict__ Af, const h16* __restrict__ Ah,
    const f16x8 bf[4][4], const float* __restrict__ bias,
    const int H, const int ch, h16* __restrict__ xp,
    const int bid, const int j)
{
    const int lane = j & 63, w = j >> 6;
    const int KF = MODE ? 4 : 2;
    float bv[4];
    #pragma unroll
    for (int g = 0; g < 4; ++g) {
        const int u = w * 16 + (lane & 15);
        bv[g] = (u < H) ? bias[g * H + u] : 0.0f;
    }
    const int ci = lane & 15, hi = lane >> 4;
    #pragma unroll
    for (int it = 0; it < NIT; ++it) {
        const int m = bid * NIT + it;
        const int bt = m / TCH, tc = m % TCH;

        f16x8 af[4];
        if (MODE == 0) {
            const int b = bt * 16 + ci;
            const int t = ch * TCH + tc;
            #pragma unroll
            for (int q = 0; q < 2; ++q) {
                const int k0 = q * 32 + hi * 8;
                const float* p = Af + ((size_t)b * T_ + t) * F_ + k0;
                float4 x0 = *(const float4*)p;
                float4 x1 = *(const float4*)(p + 4);
                uint4 r;
                r.x = pk2(x0.x, x0.y); r.y = pk2(x0.z, x0.w);
                r.z = pk2(x1.x, x1.y); r.w = pk2(x1.z, x1.w);
                af[q] = __builtin_bit_cast(f16x8, r);
            }
        } else {
            #pragma unroll
            for (int q = 0; q < 4; ++q) {
                const int k0 = q * 32 + hi * 8;
                const size_t base = ((size_t)(bt * TCH + tc) * KP + k0) * 16 + ci;
                f16x8 a;
                #pragma unroll
                for (int e = 0; e < 8; ++e) a[e] = Ah[base + (size_t)e * 16];
                af[q] = a;
            }
        }

        f32x4 acc[4];
        #pragma unroll
        for (int g = 0; g < 4; ++g) { acc[g][0]=bv[g]; acc[g][1]=bv[g]; acc[g][2]=bv[g]; acc[g][3]=bv[g]; }
        #pragma unroll
        for (int g = 0; g < 4; ++g)
            #pragma unroll
            for (int q = 0; q < 4; ++q)
                if (q < KF) acc[g] = mfma16(af[q], bf[g][q], acc[g]);

        #pragma unroll
        for (int g = 0; g < 4; ++g) {
            const int c = (w * 4 + g) * 16 + ci;
            const size_t o = ((size_t)(bt * TCH + tc) * NPC + c) * 16 + hi * 4;
            uint2 s;
            s.x = pk2(acc[g][0], acc[g][1]);
            s.y = pk2(acc[g][2], acc[g][3]);
            *(uint2*)(xp + o) = s;
        }
    }
}

// packed-weight front-end
template<int MODE, int NIT>
__device__ __forceinline__ void dense_body(
    const float* __restrict__ Af, const h16* __restrict__ Ah,
    const h16* __restrict__ Wf, const float* __restrict__ bias,
    const int H, const int ch, h16* __restrict__ xp,
    const int bid, const int j)
{
    const int lane = j & 63, w = j >> 6;
    const int KF = MODE ? 4 : 2;
    f16x8 bf[4][4];
    #pragma unroll
    for (int g = 0; g < 4; ++g)
        #pragma unroll
        for (int q = 0; q < 4; ++q)
            if (q < KF)
                bf[g][q] = *(const f16x8*)(Wf + (size_t)(((w * 4 + g) * 4 + q) * 64 + lane) * 8);
    dense_core<MODE, NIT>(Af, Ah, bf, bias, H, ch, xp, bid, j);
}

// strided front-end (prepack-rider: w1f not yet written)
template<int MODE, int NIT>
__device__ __forceinline__ void dense_body_strided(
    const float* __restrict__ Af, const h16* __restrict__ Ah,
    const float* __restrict__ W, const float* __restrict__ bias,
    const int H, const int ch, h16* __restrict__ xp,
    const int bid, const int j)
{
    const int lane = j & 63, w = j >> 6;
    const int KF = MODE ? 4 : 2;
    const int KREAL = MODE ? H1_ : 64;
    f16x8 bf[4][4];
    #pragma unroll
    for (int g = 0; g < 4; ++g)
        #pragma unroll
        for (int q = 0; q < 4; ++q)
            if (q < KF) bf[g][q] = load_bfrag(W, H, 4 * H, KREAL, w * 16, g, q, lane);
    dense_core<MODE, NIT>(Af, Ah, bf, bias, H, ch, xp, bid, j);
}

// ================= prepack + dense1(0) rider =================
// blocks 0-31: pack U1/U2/W1/W2 fragments. blocks 32-287: dense1(0) via strided W1.
__global__ __launch_bounds__(512) void k_prepack_d1(
    const float* __restrict__ U1, const float* __restrict__ U2,
    const float* __restrict__ W1, const float* __restrict__ W2,
    h16* __restrict__ u1f, h16* __restrict__ u2f,
    h16* __restrict__ w1f, h16* __restrict__ w2f,
    const float* __restrict__ x, const float* __restrict__ b1,
    h16* __restrict__ xp1w)
{
    const int bid = blockIdx.x;
    if (bid < 32) {
        const int w = bid & 7;
        const int which = bid >> 3;   // 0:U1 1:U2 2:W1 3:W2
        const float* P; int H, K, KF; h16* D;
        if (which == 0)      { P = U1; H = H1_; K = H1_; KF = 4; D = u1f; }
        else if (which == 1) { P = U2; H = H2_; K = H2_; KF = 4; D = u2f; }
        else if (which == 2) { P = W1; H = H1_; K = 64;  KF = 2; D = w1f; }
        else                 { P = W2; H = H2_; K = H1_; KF = 4; D = w2f; }
        const int lane = threadIdx.x & 63;
        #pragma unroll
        for (int it = 0; it < 2; ++it) {
            const int combo = it * 8 + (threadIdx.x >> 6);
            const int g = combo >> 2, q = combo & 3;
            if (q < KF) {
                f16x8 fr = load_bfrag(P, H, 4 * H, K, w * 16, g, q, lane);
                *(f16x8*)(D + (size_t)(((w * 4 + g) * 4 + q) * 64 + lane) * 8) = fr;
            }
        }
    } else {
        dense_body_strided<0, 2>(x, (const h16*)nullptr, W1, b1, H1_, 0, xp1w,
                                 bid - 32, threadIdx.x);
    }
}

// ================= recurrence body (R17, unchanged) =================
#define LF(G,Q) f16x8 wf##G##Q = *(const f16x8*)(Uf + (size_t)(((w*4+G)*4+Q)*64 + lane)*8);

#define RSTEP(Pn, tcur)                                                          \
    {                                                                            \
        const int t_ = (tcur);                                                   \
        const h16* hb = &hbuf[t_ & 1][0][0];                                     \
        f16x8 a0 = *(const f16x8*)(hb + ci * 136 + 0  + hi * 8);                 \
        f16x8 a1 = *(const f16x8*)(hb + ci * 136 + 32 + hi * 8);                 \
        f16x8 a2 = *(const f16x8*)(hb + ci * 136 + 64 + hi * 8);                 \
        f16x8 a3 = *(const f16x8*)(hb + ci * 136 + 96 + hi * 8);                 \
        f32x4 z0 = up4(Pn##0), z1 = up4(Pn##1), z2 = up4(Pn##2), z3 = up4(Pn##3);\
        const uint to_ = (uint)((t_ + 2 < TCH) ? t_ + 2 : t_) * xstep;           \
        Pn##0 = *(const uint2*)(xp + xb0 + to_);                                 \
        Pn##1 = *(const uint2*)(xp + xb1 + to_);                                 \
        Pn##2 = *(const uint2*)(xp + xb2 + to_);                                 \
        Pn##3 = *(const uint2*)(xp + xb3 + to_);                                 \
        z0 = mfma16(a0, wf00, z0); z0 = mfma16(a1, wf01, z0);                    \
        z0 = mfma16(a2, wf02, z0); z0 = mfma16(a3, wf03, z0);                    \
        z1 = mfma16(a0, wf10, z1); z1 = mfma16(a1, wf11, z1);                    \
        z1 = mfma16(a2, wf12, z1); z1 = mfma16(a3, wf13, z1);                    \
        z2 = mfma16(a0, wf20, z2); z2 = mfma16(a1, wf21, z2);                    \
        z2 = mfma16(a2, wf22, z2); z2 = mfma16(a3, wf23, z2);                    \
        z3 = mfma16(a0, wf30, z3); z3 = mfma16(a1, wf31, z3);                    \
        z3 = mfma16(a2, wf32, z3); z3 = mfma16(a3, wf33, z3);                    \
        f32x4 hv;                                                                \
        _Pragma("unroll")                                                        \
        for (int i = 0; i < 4; ++i) {                                            \
            float ig = sigm(z0[i]);                                              \
            float fg = sigm(z1[i]);                                              \
            float gg = fmaxf(z2[i], 0.0f);                                       \
            float og = sigm(z3[i]);                                              \
            c[i] = fg * c[i] + ig * gg;                                          \
            hv[i] = og * fmaxf(c[i], 0.0f);                                      \
        }                                                                        \
        h16 h0 = (h16)hv[0], h1 = (h16)hv[1], h2 = (h16)hv[2], h3 = (h16)hv[3]; \
        const int nb_ = (t_ & 1) ^ 1;                                            \
        hbuf[nb_][r0 + 0][myu] = h0;                                             \
        hbuf[nb_][r0 + 1][myu] = h1;                                             \
        hbuf[nb_][r0 + 2][myu] = h2;                                             \
        hbuf[nb_][r0 + 3][myu] = h3;                                             \
        h16x2 p01_; p01_.x = h0; p01_.y = h1;                                    \
        h16x2 p23_; p23_.x = h2; p23_.y = h3;                                    \
        hp.x = __builtin_bit_cast(uint, p01_);                                   \
        hp.y = __builtin_bit_cast(uint, p23_);                                   \
        if (do_hout) *(uint2*)(hout + hob + (uint)t_ * hstep) = hp;              \
        bar_lgkm();                                                              \
    }

__device__ __forceinline__ void rec_body(
    const h16* __restrict__ Uf,
    const h16* __restrict__ xp, h16* __restrict__ hout, const int do_hout,
    float* __restrict__ cstate, h16* __restrict__ hstate, const int ch,
    const int bt, const int j)
{
    __shared__ h16 hbuf[2][16][136];
    const int lane = j & 63, w = j >> 6;
    const int ci = lane & 15, hi = lane >> 4;
    const int myu = w * 16 + ci;
    const int r0 = hi * 4;

    LF(0,0) LF(0,1) LF(0,2) LF(0,3)
    LF(1,0) LF(1,1) LF(1,2) LF(1,3)
    LF(2,0) LF(2,1) LF(2,2) LF(2,3)
    LF(3,0) LF(3,1) LF(3,2) LF(3,3)

    {
        const int u = j & 127, rr = (j >> 7) * 4;
        #pragma unroll
        for (int i = 0; i < 4; ++i) {
            h16 v = (h16)0.0f;
            if (ch != 0) v = hstate[((size_t)bt * KP + u) * 16 + rr + i];
            hbuf[0][rr + i][u] = v;
        }
    }
    f32x4 c;
    const size_t coff = ((size_t)bt * KP + myu) * 16 + r0;
    if (ch == 0) { c[0]=0.f; c[1]=0.f; c[2]=0.f; c[3]=0.f; }
    else         { c = *(const f32x4*)(cstate + coff); }
    __syncthreads();

    const uint xstep = NPC * 16;
    const uint xb0 = (uint)(((size_t)bt * TCH) * NPC + (w * 64 + ci)) * 16 + r0;
    const uint xb1 = xb0 + 16 * 16, xb2 = xb0 + 32 * 16, xb3 = xb0 + 48 * 16;

    uint2 pA0 = *(const uint2*)(xp + xb0);
    uint2 pA1 = *(const uint2*)(xp + xb1);
    uint2 pA2 = *(const uint2*)(xp + xb2);
    uint2 pA3 = *(const uint2*)(xp + xb3);
    uint2 pB0 = *(const uint2*)(xp + xb0 + xstep);
    uint2 pB1 = *(const uint2*)(xp + xb1 + xstep);
    uint2 pB2 = *(const uint2*)(xp + xb2 + xstep);
    uint2 pB3 = *(const uint2*)(xp + xb3 + xstep);

    const uint hstep = KP * 16;
    const uint hob = (uint)(((size_t)bt * TCH) * KP + myu) * 16 + r0;

    uint2 hp; hp.x = 0u; hp.y = 0u;

    for (int tt = 0; tt < TCH; tt += 2) {
        RSTEP(pA, tt)
        RSTEP(pB, tt + 1)
    }

    *(f32x4*)(cstate + coff) = c;
    *(uint2*)(hstate + ((size_t)bt * KP + myu) * 16 + r0) = hp;
}

// ================= unified mega-dispatch =================
// blocks 0-15: rec2 | 16-31: rec1 | 32-287: dense2 rider | 288-543: dense1 rider
__global__ __launch_bounds__(512) void k_mega(
    const int rec2_on, const h16* __restrict__ Uf2, const h16* __restrict__ xp2r,
    float* __restrict__ c2, h16* __restrict__ hs2, const int ch2,
    const int rec1_on, const h16* __restrict__ Uf1, const h16* __restrict__ xp1r,
    h16* __restrict__ h1gw, float* __restrict__ c1, h16* __restrict__ hs1, const int ch1,
    const int d2_on, const h16* __restrict__ h1gr, const h16* __restrict__ w2f,
    const float* __restrict__ b2, h16* __restrict__ xp2w,
    const int d1_on, const float* __restrict__ x, const h16* __restrict__ w1f,
    const float* __restrict__ b1, const int chd1, h16* __restrict__ xp1w)
{
    const int bid = blockIdx.x, j = threadIdx.x;
    if (bid < 16) {
        if (rec2_on) rec_body(Uf2, xp2r, (h16*)nullptr, 0, c2, hs2, ch2, bid, j);
    } else if (bid < 32) {
        if (rec1_on) rec_body(Uf1, xp1r, h1gw, 1, c1, hs1, bid == 16 ? ch1 : ch1, bid - 16, j);
    } else if (bid < 288) {
        if (d2_on) dense_body<1, 2>((const float*)nullptr, h1gr, w2f, b2, H2_, 0, xp2w, bid - 32, j);
    } else {
        if (d1_on) dense_body<0, 2>(x, (const h16*)nullptr, w1f, b1, H1_, chd1, xp1w, bid - 288, j);
    }
}

// ================= head =================
__global__ void k_head(const h16* __restrict__ h2s, const float* __restrict__ Wd,
                       const float* __restrict__ bd, float* __restrict__ out)
{
    __shared__ float lg[OUT_];
    const int b = blockIdx.x, j = threadIdx.x;
    const int bt = b >> 4, r = b & 15;
    if (j < OUT_) {
        float acc = bd[j];
        for (int u = 0; u < H2_; ++u)
            acc += (float)h2s[((size_t)bt * KP + u) * 16 + r] * Wd[u * OUT_ + j];
        lg[j] = acc;
    }
    __syncthreads();
    if (j < OUT_) {
        float m = -1e30f;
        for (int k = 0; k < OUT_; ++k) m = fmaxf(m, lg[k]);
        float s = 0.0f;
        for (int k = 0; k < OUT_; ++k) s += expf(lg[k] - m);
        out[b * OUT_ + j] = expf(lg[j] - m) / s;
    }
}

// ================= R9 fallback (known-good) =================
#define G1_  400
#define G2_  512
#define FBTC 32
#define FB_XP1  0
#define FB_XP2  0
#define FB_WQ   51200
#define FB_XS   134400
#define FB_W2Q  32768
#define FB_H1C  139264
#define FB_U2Q  32768
#define FB_ZBUF 160000
#define FB_H1PK 162048
#define FB_H2PK 162256
#define FB_H2F  162512
#define FB_LDS  163328

__device__ __forceinline__ float fd2(uint wv, uint hv, float cc) {
#if __has_builtin(__builtin_amdgcn_fdot2)
    return __builtin_amdgcn_fdot2(__builtin_bit_cast(h16x2, wv),
                                  __builtin_bit_cast(h16x2, hv), cc, false);
#else
    h16x2 a = __builtin_bit_cast(h16x2, wv), b = __builtin_bit_cast(h16x2, hv);
    return cc + (float)a.x * (float)b.x + (float)a.y * (float)b.y;
#endif
}

__device__ __forceinline__ void stage_quads(const float* __restrict__ P, const int G,
                                            const int NQ, const int KREAL,
                                            char* dst, const int j)
{
    if (j < G) {
        for (int q = 0; q < NQ; ++q) {
            float f[8];
            #pragma unroll
            for (int r = 0; r < 8; ++r) {
                const int k = 8 * q + r;
                f[r] = (k < KREAL) ? P[(size_t)k * G + j] : 0.0f;
            }
            uint4 u;
            u.x = pk2(f[0], f[1]); u.y = pk2(f[2], f[3]);
            u.z = pk2(f[4], f[5]); u.w = pk2(f[6], f[7]);
            *(uint4*)(dst + (size_t)(q * G + j) * 16) = u;
        }
    }
}

__global__ __launch_bounds__(512) void lstm_fallback(
    const float* __restrict__ x,
    const float* __restrict__ W1, const float* __restrict__ U1, const float* __restrict__ b1,
    const float* __restrict__ W2, const float* __restrict__ U2, const float* __restrict__ b2,
    const float* __restrict__ Wd, const float* __restrict__ bd,
    float* __restrict__ out)
{
    __shared__ uint4 smem4[FB_LDS / 16];
    char* sm = (char*)smem4;
    const int b = blockIdx.x;
    const int j = threadIdx.x;
    float c1 = 0.0f, c2 = 0.0f;

    const uint u2r0 = pk2(U2[120 * G2_ + j], U2[121 * G2_ + j]);
    const uint u2r1 = pk2(U2[122 * G2_ + j], U2[123 * G2_ + j]);
    const uint u2r2 = pk2(U2[124 * G2_ + j], U2[125 * G2_ + j]);
    const uint u2r3 = pk2(U2[126 * G2_ + j], U2[127 * G2_ + j]);

    if (j < 52) *(uint*)(sm + FB_H1PK + 4 * j) = 0u;
    if (j < 64) *(uint*)(sm + FB_H2PK + 4 * j) = 0u;
    __syncthreads();

    const float* xrow = x + (size_t)b * T_ * F_;
    for (int ch = 0; ch < T_ / FBTC; ++ch) {
        stage_quads(W1, G1_, 8, 64, sm + FB_WQ, j);
        #pragma unroll
        for (int r = 0; r < 2; ++r) {
            int v = r * 512 + j;
            float2 xv = *(const float2*)(xrow + ch * (FBTC * F_) + 2 * v);
            *(uint*)(sm + FB_XS + 4 * v) = pk2(xv.x, xv.y);
        }
        __syncthreads();
        if (j < G1_) {
            const float bj = b1[j];
            const uint4* WQ = (const uint4*)(sm + FB_WQ);
            for (int t = 0; t < FBTC; ++t) {
                const uint4* XQ = (const uint4*)(sm + FB_XS + t * 128);
                float a0 = bj, a1 = 0.f, a2 = 0.f, a3 = 0.f;
                #pragma unroll
                for (int q = 0; q < 8; ++q) {
                    uint4 wq = WQ[q * G1_ + j]; uint4 hq = XQ[q];
                    a0 = fd2(wq.x, hq.x, a0); a1 = fd2(wq.y, hq.y, a1);
                    a2 = fd2(wq.z, hq.z, a2); a3 = fd2(wq.w, hq.w, a3);
                }
                *(float*)(sm + FB_XP1 + 4 * (t * G1_ + j)) = (a0 + a1) + (a2 + a3);
            }
        }
        __syncthreads();
        stage_quads(U1, G1_, 13, H1_, sm + FB_WQ, j);
        __syncthreads();
        for (int t = 0; t < FBTC; ++t) {
            if (j < G1_) {
                const uint4* WQ = (const uint4*)(sm + FB_WQ);
                const uint4* HP = (const uint4*)(sm + FB_H1PK);
                float a0 = *(const float*)(sm + FB_XP1 + 4 * (t * G1_ + j));
                float a1 = 0.f, a2 = 0.f, a3 = 0.f;
                #pragma unroll
                for (int q = 0; q < 13; ++q) {
                    uint4 wq = WQ[q * G1_ + j]; uint4 hq = HP[q];
                    a0 = fd2(wq.x, hq.x, a0); a1 = fd2(wq.y, hq.y, a1);
                    a2 = fd2(wq.z, hq.z, a2); a3 = fd2(wq.w, hq.w, a3);
                }
                *(float*)(sm + FB_ZBUF + 4 * j) = (a0 + a1) + (a2 + a3);
            }
            __syncthreads();
            if (j < H1_) {
                const float* zb = (const float*)(sm + FB_ZBUF);
                float ig = sigm(zb[j]);
                float fg = sigm(zb[H1_ + j]);
                float gg = fmaxf(zb[2 * H1_ + j], 0.0f);
                float og = sigm(zb[3 * H1_ + j]);
                c1 = fg * c1 + ig * gg;
                float h = og * fmaxf(c1, 0.0f);
                h16 hh = (h16)h;
                *(h16*)(sm + FB_H1PK + 2 * j) = hh;
                *(h16*)(sm + FB_H1C + t * 208 + 2 * j) = hh;
            }
            __syncthreads();
        }
        stage_quads(W2, G2_, 13, H1_, sm + FB_W2Q, j);
        __syncthreads();
        {
            const float bj = b2[j];
            const uint4* WQ = (const uint4*)(sm + FB_W2Q);
            for (int t = 0; t < FBTC; ++t) {
                const uint4* HC = (const uint4*)(sm + FB_H1C + t * 208);
                float a0 = bj, a1 = 0.f, a2 = 0.f, a3 = 0.f;
                #pragma unroll
                for (int q = 0; q < 13; ++q) {
                    uint4 wq = WQ[q * G2_ + j]; uint4 hq = HC[q];
                    a0 = fd2(wq.x, hq.x, a0); a1 = fd2(wq.y, hq.y, a1);
                    a2 = fd2(wq.z, hq.z, a2); a3 = fd2(wq.w, hq.w, a3);
                }
                *(h16*)(sm + FB_XP2 + 2 * (t * G2_ + j)) = (h16)((a0 + a1) + (a2 + a3));
            }
        }
        __syncthreads();
        stage_quads(U2, G2_, 15, 120, sm + FB_U2Q, j);
        __syncthreads();
        for (int t = 0; t < FBTC; ++t) {
            {
                const uint4* WQ = (const uint4*)(sm + FB_U2Q);
                const uint4* HP = (const uint4*)(sm + FB_H2PK);
                float a0 = (float)*(const h16*)(sm + FB_XP2 + 2 * (t * G2_ + j));
                float a1 = 0.f, a2 = 0.f, a3 = 0.f;
                #pragma unroll
                for (int q = 0; q < 15; ++q) {
                    uint4 wq = WQ[q * G2_ + j]; uint4 hq = HP[q];
                    a0 = fd2(wq.x, hq.x, a0); a1 = fd2(wq.y, hq.y, a1);
                    a2 = fd2(wq.z, hq.z, a2); a3 = fd2(wq.w, hq.w, a3);
                }
                uint4 hp15 = ((const uint4*)(sm + FB_H2PK))[15];
                a0 = fd2(u2r0, hp15.x, a0); a1 = fd2(u2r1, hp15.y, a1);
                a2 = fd2(u2r2, hp15.z, a2); a3 = fd2(u2r3, hp15.w, a3);
                *(float*)(sm + FB_ZBUF + 4 * j) = (a0 + a1) + (a2 + a3);
            }
            __syncthreads();
            if (j < H2_) {
                const float* zb = (const float*)(sm + FB_ZBUF);
                float ig = sigm(zb[j]);
                float fg = sigm(zb[H2_ + j]);
                float gg = fmaxf(zb[2 * H2_ + j], 0.0f);
                float og = sigm(zb[3 * H2_ + j]);
                c2 = fg * c2 + ig * gg;
                float h = og * fmaxf(c2, 0.0f);
                *(h16*)(sm + FB_H2PK + 2 * j) = (h16)h;
                *(float*)(sm + FB_H2F + 4 * j) = h;
            }
            __syncthreads();
        }
    }
    if (j < OUT_) {
        const float* h2 = (const float*)(sm + FB_H2F);
        float acc = bd[j];
        #pragma unroll
        for (int k = 0; k < H2_; ++k) acc += h2[k] * Wd[k * OUT_ + j];
        *(float*)(sm + FB_ZBUF + 4 * j) = acc;
    }
    __syncthreads();
    if (j < OUT_) {
        const float* zb = (const float*)(sm + FB_ZBUF);
        float m = -1e30f;
        for (int k = 0; k < OUT_; ++k) m = fmaxf(m, zb[k]);
        float s = 0.0f;
        for (int k = 0; k < OUT_; ++k) s += expf(zb[k] - m);
        out[b * OUT_ + j] = expf(zb[j] - m) / s;
    }
}

// ================= launcher =================
extern "C" void kernel_launch(void* const* d_in, const int* in_sizes, int n_in,
                              void* d_out, int out_size, void* d_ws, size_t ws_size,
                              hipStream_t stream) {
    const float* x  = (const float*)d_in[0];
    const float* W1 = (const float*)d_in[1];
    const float* U1 = (const float*)d_in[2];
    const float* b1 = (const float*)d_in[3];
    const float* W2 = (const float*)d_in[4];
    const float* U2 = (const float*)d_in[5];
    const float* b2 = (const float*)d_in[6];
    const float* Wd = (const float*)d_in[7];
    const float* bd = (const float*)d_in[8];
    float* out = (float*)d_out;

    if (ws_size >= WS_A) {
        char* ws = (char*)d_ws;
        h16* xp1[2] = { (h16*)(ws + A_XP1A), (h16*)(ws + A_XP1B) };
        h16* xp2[2] = { (h16*)(ws + A_XP2A), (h16*)(ws + A_XP2B) };
        h16* h1g[2] = { (h16*)(ws + A_H1GA), (h16*)(ws + A_H1GB) };
        float* c1  = (float*)(ws + A_C1);
        float* c2  = (float*)(ws + A_C2);
        h16*   hs1 = (h16*)(ws + A_H1S);
        h16*   hs2 = (h16*)(ws + A_H2S);
        h16*   u1f = (h16*)(ws + A_U1F);
        h16*   u2f = (h16*)(ws + A_U2F);
        h16*   w1f = (h16*)(ws + A_W1F);
        h16*   w2f = (h16*)(ws + A_W2F);

        // prepack + dense1(0) rider (strided W1 gather, independent of w1f)
        k_prepack_d1<<<288, 512, 0, stream>>>(U1, U2, W1, W2, u1f, u2f, w1f, w2f,
                                              x, b1, xp1[0]);
        // P-1: rec1(0) -> h1g[0]; rider dense1(1) -> xp1[1]
        k_mega<<<544, 512, 0, stream>>>(
            0, u2f, (const h16*)nullptr, c2, hs2, 0,
            1, u1f, xp1[0], h1g[0], c1, hs1, 0,
            0, (const h16*)nullptr, w2f, b2, (h16*)nullptr,
            1, x, w1f, b1, 1, xp1[1]);
        // P0: rec1(1) -> h1g[1]; riders dense2(0) -> xp2[0], dense1(2) -> xp1[0]
        k_mega<<<544, 512, 0, stream>>>(
            0, u2f, (const h16*)nullptr, c2, hs2, 0,
            1, u1f, xp1[1], h1g[1], c1, hs1, 1,
            1, h1g[0], w2f, b2, xp2[0],
            1, x, w1f, b1, 2, xp1[0]);
        for (int ch = 0; ch < NCH; ++ch) {
            const int r1on = (ch + 2 < NCH);
            const int d2on = (ch + 1 < NCH);
            const int d1on = (ch + 3 < NCH);
            k_mega<<<544, 512, 0, stream>>>(
                1, u2f, xp2[ch & 1], c2, hs2, ch,
                r1on, u1f, xp1[(ch + 2) & 1], h1g[(ch + 2) & 1], c1, hs1, ch + 2,
                d2on, h1g[(ch + 1) & 1], w2f, b2, xp2[(ch + 1) & 1],
                d1on, x, w1f, b1, ch + 3, xp1[(ch + 3) & 1]);
        }
        k_head<<<256, 64, 0, stream>>>(hs2, Wd, bd, out);
    } else {
        lstm_fallback<<<B_, 512, 0, stream>>>(x, W1, U1, b1, W2, U2, b2, Wd, bd, out);
    }
}